// Round 8
// baseline (166.952 us; speedup 1.0000x reference)
//
#include <hip/hip_runtime.h>

#define NA 384
#define NB 384
#define NBATCH 64
#define NEGV -1e20f
#define C 8            // steps per chunk
#define NCW 6          // compute waves (rows 64w+1..64w+64)
#define TOT_CH 56      // chunks: s0 = 1 + 8k, k = 0..55
#define WPITCH 68      // wtile row pitch (floats)
#define LOG2E 1.44269504088896340736f
#define LN2   0.69314718055994530942f

typedef float f4 __attribute__((ext_vector_type(4)));

struct alignas(16) SharedT {
    float stage[2][NCW][64 * 9];      // mu staging ring (log2 domain)
    float wtile[4][NCW][8 * WPITCH];  // transposed W ring, 4 deep
    float bound[NCW - 1][NB + 1];     // boundary rows mu'[64w][1..384]
    int   progress[NCW - 1];
    int   computed[NCW];
    int   drained[NCW][2];
    int   wready[NCW];                // highest chunk+1 whose wtile is ready
};

// Skewed-coalesced W load for chunk kk: instr i covers rows 8i..8i+7 x 8
// consecutive cols (8 cache lines/instr). lane l -> W[row][col],
// row = 8i + (l>>3), col = 8kk + (l&7) - row (clamped; clamped vals unused).
__device__ __forceinline__ void loadW8(const float* __restrict__ Wb, int rbase,
                                       int kk, int l, float (&r)[8])
{
    const int rl = l >> 3, cc = l & 7;
    const int colb = 8 * kk + cc;
#pragma unroll
    for (int i = 0; i < 8; ++i) {
        const int row = 8 * i + rl;
        int col = colb - row;
        col = col < 0 ? 0 : (col > NB - 1 ? NB - 1 : col);
        r[i] = Wb[(size_t)(rbase + row) * NB + col];
    }
}

__device__ __forceinline__ void writeWt(float* __restrict__ wt,
                                        const float (&r)[8], int l) {
#pragma unroll
    for (int i = 0; i < 8; ++i) wt[i * WPITCH + l] = r[i];
}

// lane l's 8 consecutive W values for a chunk, premultiplied by LOG2E
__device__ __forceinline__ void readWc(const float* __restrict__ wt, int l,
                                       float (&wc)[8]) {
    const int wb = (l >> 3) * WPITCH + (l & 7) * 8;
    const f4 lo = *(const f4*)(wt + wb);
    const f4 hi = *(const f4*)(wt + wb + 4);
    wc[0] = lo.x * LOG2E; wc[1] = lo.y * LOG2E;
    wc[2] = lo.z * LOG2E; wc[3] = lo.w * LOG2E;
    wc[4] = hi.x * LOG2E; wc[5] = hi.y * LOG2E;
    wc[6] = hi.z * LOG2E; wc[7] = hi.w * LOG2E;
}

// ---------------- compute (relay) chunk ----------------
template<bool FULL>
__device__ __forceinline__ void chunk_body(int k, int w, int l,
        float (&wc)[8], float& val, float& diag, SharedT& sh)
{
    const int s0 = 1 + k * C;

    // stage ring slot free? (expected pass)
    if (k >= 2) {
        volatile int* dr = &sh.drained[w][k & 1];
        while (*dr < k - 2) __builtin_amdgcn_s_sleep(1);
        __builtin_amdgcn_sched_barrier(0);
        asm volatile("" ::: "memory");
    }
    // producer boundary ready? (bare spin: THE latency-critical relay edge)
    if (w > 0 && s0 <= NB) {
        const int need = (s0 + C - 1 < NB) ? s0 + C - 1 : NB;
        volatile int* pr = &sh.progress[w - 1];
        while (*pr < need) { }
        __builtin_amdgcn_sched_barrier(0);
        asm volatile("" ::: "memory");
    }
    float bnd[C];
    if (w > 0) {
#pragma unroll
        for (int c = 0; c < C; ++c) {
            const int s = s0 + c;
            bnd[c] = sh.bound[w - 1][s <= NB ? s : NB];
        }
    }

    float* st = &sh.stage[k & 1][w][0];
    __builtin_amdgcn_s_setprio(1);
#pragma unroll
    for (int c = 0; c < C; ++c) {
        const int s = s0 + c;
        float upv = __int_as_float(__builtin_amdgcn_update_dpp(
            0, __float_as_int(val), 0x138 /*WAVE_SHR1*/, 0xF, 0xF, false));
        if (l == 0) upv = (w > 0 && s <= NB) ? bnd[c] : NEGV;
        const int j = s - l;
        if (FULL || (j >= 1 && j <= NB)) {
            const float m  = fmaxf(fmaxf(upv, val), diag);   // v_max3_f32
            const float eu = exp2f(upv  - m);
            const float el = exp2f(val  - m);
            const float ed = exp2f(diag - m);
            const float nv = wc[c] + m + __log2f(eu + el + ed);
            st[l * 9 + c] = nv;                              // ds_write_b32
            if (w < NCW - 1 && l == 63) sh.bound[w][j] = nv;
            diag = upv;
            val  = nv;
        }
    }
    asm volatile("s_waitcnt lgkmcnt(0)" ::: "memory");       // DS only
    if (l == 63) {
        if (w < NCW - 1) {
            const int done = s0 + C - 1 - 63;
            if (done >= 1) *(volatile int*)&sh.progress[w] = done;
        }
        *(volatile int*)&sh.computed[w] = k + 1;
    }
    __builtin_amdgcn_s_setprio(0);

    // prefetch next chunk's W fragment; wready(k+2) was published by
    // io_iter k-2, so this poll passes immediately in steady state.
    if (k + 1 < TOT_CH) {
        volatile int* wr = &sh.wready[w];
        while (*wr < k + 2) { }
        __builtin_amdgcn_sched_barrier(0);
        asm volatile("" ::: "memory");
        readWc(&sh.wtile[(k + 1) & 3][w][0], l, wc);
    }
}

// ---------------- IO iteration: drain mu, feed W ----------------
template<bool FULL>
__device__ __forceinline__ void io_iter(int k, int cw, int l,
        const float* __restrict__ Wb, int rbase, float* __restrict__ mub,
        float (&wreg)[8], SharedT& sh)
{
    // wait for staged mu chunk
    volatile int* cp = &sh.computed[cw];
    while (*cp < k + 1) __builtin_amdgcn_s_sleep(1);
    __builtin_amdgcn_sched_barrier(0);
    asm volatile("" ::: "memory");

    // stage -> regs (transposed), release ring slot immediately
    const float* st = &sh.stage[k & 1][cw][0];
    float v[8];
    const int lr = l >> 3, cc = l & 7;
#pragma unroll
    for (int q = 0; q < 8; ++q) v[q] = st[(lr + 8 * q) * 9 + cc];
    asm volatile("s_waitcnt lgkmcnt(0)" ::: "memory");
    if (l == 0) *(volatile int*)&sh.drained[cw][k & 1] = k;

    // feed W tile for chunk k+3 from wreg (loaded at io_iter k-2: the
    // vmcnt wait here is for a ~2-period-old load -> fully covered)
    if (k + 3 < TOT_CH) {
        writeWt(&sh.wtile[(k + 3) & 3][cw][0], wreg, l);
        asm volatile("s_waitcnt lgkmcnt(0)" ::: "memory");
        if (l == 0) *(volatile int*)&sh.wready[cw] = k + 4;
        if (k + 5 < TOT_CH) loadW8(Wb, rbase, k + 5, l, wreg);
    }

    // mu stores LAST (fire-and-forget, off all flag paths)
    const int colbase = k * C;
#pragma unroll
    for (int q = 0; q < 8; ++q) {
        const int lrow = lr + 8 * q;
        const int col  = colbase + cc - lrow;
        if (FULL || (col >= 0 && col < NB))
            mub[(size_t)(rbase + lrow + 1) * (NB + 1) + col + 1] = v[q] * LN2;
    }
}

__global__ __launch_bounds__(768, 1) void dtw_mu(const float* __restrict__ W,
                                                 float* __restrict__ mu)
{
    __shared__ SharedT sh;
    const int b = blockIdx.x, tid = threadIdx.x;
    const int w = tid >> 6, l = tid & 63;
    const float* Wb = W + (size_t)b * NA * NB;
    float* mub = mu + (size_t)b * (NA + 1) * (NB + 1);

    if (tid < 384) {
        mub[tid + 1] = NEGV;                          // row 0, cols 1..384
        mub[(size_t)(tid + 1) * (NB + 1)] = NEGV;     // col 0, rows 1..384
    }
    if (tid == 0) mub[0] = 0.0f;
    if (tid < NCW - 1) sh.progress[tid] = 0;
    if (tid < NCW) { sh.computed[tid] = 0; sh.wready[tid] = 0; }
    if (tid < 2 * NCW) sh.drained[tid >> 1][tid & 1] = -1;
    __syncthreads();

    if (w < NCW) {
        // ---------------- compute (relay) wave ----------------
        const int rbase = w << 6;
        float val  = NEGV;                            // mu'[r][j-1]
        float diag = (rbase + l == 0) ? 0.0f : NEGV;  // mu'[r-1][0]
        float wc[8];
        {
            volatile int* wr = &sh.wready[w];
            while (*wr < 1) { }
            __builtin_amdgcn_sched_barrier(0);
            asm volatile("" ::: "memory");
            readWc(&sh.wtile[0][w][0], l, wc);
        }
        for (int k = 0; k < 8; ++k)       chunk_body<false>(k, w, l, wc, val, diag, sh);
        for (int k = 8; k < 48; ++k)      chunk_body<true >(k, w, l, wc, val, diag, sh);
        for (int k = 48; k < TOT_CH; ++k) chunk_body<false>(k, w, l, wc, val, diag, sh);
    } else {
        // ---------------- I/O wave: W feed + mu drain ----------------
        const int cw = w - NCW, rbase = cw << 6;
        float r0[8], r1[8], r2[8], rA[8], rB[8];
        loadW8(Wb, rbase, 0, l, r0);
        loadW8(Wb, rbase, 1, l, r1);
        loadW8(Wb, rbase, 2, l, r2);
        loadW8(Wb, rbase, 3, l, rA);
        loadW8(Wb, rbase, 4, l, rB);
        writeWt(&sh.wtile[0][cw][0], r0, l);
        writeWt(&sh.wtile[1][cw][0], r1, l);
        writeWt(&sh.wtile[2][cw][0], r2, l);
        asm volatile("s_waitcnt lgkmcnt(0)" ::: "memory");
        if (l == 0) *(volatile int*)&sh.wready[cw] = 3;

        // io_iter k: drains chunk k, writes wtile for k+3 (even k from rA,
        // odd k from rB), reloads that reg set with W(k+5).
        for (int k = 0; k < 8; k += 2) {
            io_iter<false>(k,     cw, l, Wb, rbase, mub, rA, sh);
            io_iter<false>(k + 1, cw, l, Wb, rbase, mub, rB, sh);
        }
        for (int k = 8; k < 48; k += 2) {
            io_iter<true >(k,     cw, l, Wb, rbase, mub, rA, sh);
            io_iter<true >(k + 1, cw, l, Wb, rbase, mub, rB, sh);
        }
        for (int k = 48; k < TOT_CH; k += 2) {
            io_iter<false>(k,     cw, l, Wb, rbase, mub, rA, sh);
            io_iter<false>(k + 1, cw, l, Wb, rbase, mub, rB, sh);
        }
    }
}

// ---------------- pass 2: pi = exp(x + W - mu_ij) * mask ----------------
__global__ __launch_bounds__(256) void dtw_pi(const float* __restrict__ W,
        const float* __restrict__ mask, const float* __restrict__ mu,
        float* __restrict__ pi)
{
    const long long idx = ((long long)blockIdx.x * 256 + threadIdx.x) * 4;
    const int rr = (int)(idx / NB);          // b*NA + ii
    const int jj = (int)(idx - (long long)rr * NB);
    const int b  = rr / NA;
    const int ii = rr - b * NA;
    const float* m0 = mu + (size_t)b * (NA + 1) * (NB + 1)
                         + (size_t)ii * (NB + 1) + jj;     // mu[b][ii][jj..jj+4]
    const float* m1 = m0 + (NB + 1);                       // mu[b][ii+1][...]
    const float d0 = m0[0], d1 = m0[1], d2 = m0[2], d3 = m0[3], d4 = m0[4];
    const float L0 = m1[0], L1 = m1[1], L2 = m1[2], L3 = m1[3], L4 = m1[4];
    const f4 wv = *(const f4*)(W + idx);
    const f4 mk = *(const f4*)(mask + idx);

    const float t0 = wv.x - L1, t1 = wv.y - L2, t2 = wv.z - L3, t3 = wv.w - L4;
    f4 o0, o1, o2;
    o0.x = exp2f((d1 + t0) * LOG2E) * mk.x;   // c0 up
    o0.y = exp2f((L0 + t0) * LOG2E) * mk.x;   // c0 left
    o0.z = exp2f((d0 + t0) * LOG2E) * mk.x;   // c0 diag
    o0.w = exp2f((d2 + t1) * LOG2E) * mk.y;   // c1 up
    o1.x = exp2f((L1 + t1) * LOG2E) * mk.y;   // c1 left
    o1.y = exp2f((d1 + t1) * LOG2E) * mk.y;   // c1 diag
    o1.z = exp2f((d3 + t2) * LOG2E) * mk.z;   // c2 up
    o1.w = exp2f((L2 + t2) * LOG2E) * mk.z;   // c2 left
    o2.x = exp2f((d2 + t2) * LOG2E) * mk.z;   // c2 diag
    o2.y = exp2f((d4 + t3) * LOG2E) * mk.w;   // c3 up
    o2.z = exp2f((L3 + t3) * LOG2E) * mk.w;   // c3 left
    o2.w = exp2f((d3 + t3) * LOG2E) * mk.w;   // c3 diag

    f4* po = (f4*)(pi + idx * 3);             // 48B-aligned
    po[0] = o0; po[1] = o1; po[2] = o2;
}

extern "C" void kernel_launch(void* const* d_in, const int* in_sizes, int n_in,
                              void* d_out, int out_size, void* d_ws, size_t ws_size,
                              hipStream_t stream) {
    const float* W    = (const float*)d_in[0];
    const float* mask = (const float*)d_in[1];
    float* mu = (float*)d_out;
    float* pi = mu + (size_t)NBATCH * (NA + 1) * (NB + 1);

    hipLaunchKernelGGL(dtw_mu, dim3(NBATCH), dim3(768), 0, stream, W, mu);

    const int cells  = NBATCH * NA * NB;              // 9437184
    const int blocks = cells / (256 * 4);             // 9216
    hipLaunchKernelGGL(dtw_pi, dim3(blocks), dim3(256), 0, stream,
                       W, mask, mu, pi);
}